// Round 10
// baseline (351.640 us; speedup 1.0000x reference)
//
#include <hip/hip_runtime.h>

#define NV 50000
#define NE 800000
#define CVT_N 1600000
#define TR_N  81920
#define W3N_N 16384
#define B3N_N 128
#define NB1 49        // ceil(NV/1024)
#define NB_ZERO 6250  // agg2 zeroing blocks (25.6MB / (256 thr * 16B))
#define NB_PERM 3125  // NE/256
#define NB_H1 196     // ceil(NV/256)

typedef _Float16 f16x8 __attribute__((ext_vector_type(8)));
typedef _Float16 f16x4 __attribute__((ext_vector_type(4)));
typedef float    f32x4 __attribute__((ext_vector_type(4)));

static __device__ __forceinline__ f32x4 mfma16(f16x8 a, f16x8 b, f32x4 c) {
  return __builtin_amdgcn_mfma_f32_16x16x32_f16(a, b, c, 0, 0, 0);
}

// ---- fused prep: h->f16, 5 128x128 transposes (f16), W3n fold, b3n, hist ----
__global__ void prep_kernel(const float* __restrict__ h, _Float16* __restrict__ hf,
    const float* __restrict__ W1, const float* __restrict__ W2, const float* __restrict__ W3,
    const float* __restrict__ Wn1, const float* __restrict__ Wn2, const float* __restrict__ b3,
    _Float16* __restrict__ w1st, _Float16* __restrict__ w1dt, _Float16* __restrict__ w2t,
    _Float16* __restrict__ wn1c, _Float16* __restrict__ wn2t, float* __restrict__ b3n,
    const int* __restrict__ ei, int* __restrict__ counts)
{
  int i = blockIdx.x * blockDim.x + threadIdx.x;
  if (i < CVT_N) {
    f32x4 v = reinterpret_cast<const f32x4*>(h)[i];
    f16x4 o;
    o[0] = (_Float16)v[0]; o[1] = (_Float16)v[1]; o[2] = (_Float16)v[2]; o[3] = (_Float16)v[3];
    reinterpret_cast<f16x4*>(hf)[i] = o;
    return;
  }
  i -= CVT_N;
  if (i < TR_N) {
    int seg = i >> 14;
    int j = i & 16383;
    int f = j >> 7, k = j & 127;
    switch (seg) {
      case 0: w1st[j] = (_Float16)W1[k * 128 + f]; break;         // W1top^T
      case 1: w1dt[j] = (_Float16)W1[(k + 128) * 128 + f]; break; // W1bot^T
      case 2: w2t[j]  = (_Float16)W2[k * 128 + f]; break;
      case 3: wn1c[f * 256 + k] = (_Float16)Wn1[k * 128 + f]; break;
      case 4: wn2t[j] = (_Float16)Wn2[k * 128 + f]; break;
    }
    return;
  }
  i -= TR_N;
  if (i < W3N_N) {   // wn1c[f][128+ii] = sum_j W3[ii][j] * Wn1[128+j][f]
    int f = i >> 7, ii = i & 127;
    float a = 0.f;
    for (int j = 0; j < 128; j++) a += W3[ii * 128 + j] * Wn1[(128 + j) * 128 + f];
    wn1c[f * 256 + 128 + ii] = (_Float16)a;
    return;
  }
  i -= W3N_N;
  if (i < B3N_N) {
    float a = 0.f;
    for (int j = 0; j < 128; j++) a += b3[j] * Wn1[(128 + j) * 128 + i];
    b3n[i] = a;
    return;
  }
  i -= B3N_N;
  if (i < NE) atomicAdd(&counts[ei[NE + i]], 1);
}

// ---- block sums ----
__global__ __launch_bounds__(1024)
void bsum_kernel(const int* __restrict__ counts, int* __restrict__ bsum) {
  __shared__ int red[1024];
  const int t = threadIdx.x;
  int i = blockIdx.x * 1024 + t;
  red[t] = (i < NV) ? counts[i] : 0;
  __syncthreads();
  for (int off = 512; off > 0; off >>= 1) {
    if (t < off) red[t] += red[t + off];
    __syncthreads();
  }
  if (t == 0) bsum[blockIdx.x] = red[0];
}

// ---- offsets: block-local scan + inline base (butterfly over 49 block sums) ----
__global__ __launch_bounds__(1024)
void offs_kernel(const int* __restrict__ counts, const int* __restrict__ bsum,
                 int* __restrict__ offsets, int* __restrict__ cursor) {
  __shared__ int s[1024];
  __shared__ int sbase;
  const int t = threadIdx.x;
  int i = blockIdx.x * 1024 + t;
  int v = (i < NV) ? counts[i] : 0;
  s[t] = v;
  if (t < 64) {
    int x = (t < blockIdx.x) ? bsum[t] : 0;   // NB1=49 <= 64
    for (int off = 1; off < 64; off <<= 1) x += __shfl_xor(x, off);
    if (t == 0) sbase = x;
  }
  __syncthreads();
  for (int off = 1; off < 1024; off <<= 1) {
    int x = (t >= off) ? s[t - off] : 0;
    __syncthreads();
    s[t] += x;
    __syncthreads();
  }
  if (i < NV) {
    int excl = sbase + s[t] - v;
    offsets[i] = excl;
    cursor[i] = excl;
    if (i == NV - 1) offsets[NV] = sbase + s[t];
  }
}

// ---- one K=128 GEMM (64 rows x 128 feats per wave), f16 ----
static __device__ __forceinline__ void gemm128_rows(
    const _Float16* __restrict__ hf, const int* nid, const _Float16* __restrict__ At,
    const float* __restrict__ bias, _Float16* __restrict__ Out,
    int nbase, int l15, int quad)
{
  f32x4 acc[8][4];
#pragma unroll
  for (int mt = 0; mt < 8; mt++)
#pragma unroll
    for (int nt = 0; nt < 4; nt++)
      acc[mt][nt] = (f32x4){0.f, 0.f, 0.f, 0.f};

  f16x8 Bc[4], Bn[4];
#pragma unroll
  for (int nt = 0; nt < 4; nt++)
    Bc[nt] = *reinterpret_cast<const f16x8*>(hf + (long long)nid[nt] * 128 + quad * 8);
#pragma unroll
  for (int s = 0; s < 4; s++) {
    if (s < 3) {
#pragma unroll
      for (int nt = 0; nt < 4; nt++)
        Bn[nt] = *reinterpret_cast<const f16x8*>(hf + (long long)nid[nt] * 128 + (s + 1) * 32 + quad * 8);
    }
    const int k = s * 32 + quad * 8;
#pragma unroll
    for (int mt = 0; mt < 8; mt++) {
      f16x8 A = *reinterpret_cast<const f16x8*>(At + (mt * 16 + l15) * 128 + k);
#pragma unroll
      for (int nt = 0; nt < 4; nt++)
        acc[mt][nt] = mfma16(A, Bc[nt], acc[mt][nt]);
    }
#pragma unroll
    for (int nt = 0; nt < 4; nt++) Bc[nt] = Bn[nt];
  }
#pragma unroll
  for (int mt = 0; mt < 8; mt++) {
    f32x4 bb = bias ? *reinterpret_cast<const f32x4*>(bias + mt * 16 + quad * 4)
                    : (f32x4){0.f, 0.f, 0.f, 0.f};
#pragma unroll
    for (int nt = 0; nt < 4; nt++) {
      int n = nbase + nt * 16 + l15;
      if (n < NV) {
        f16x4 o;
#pragma unroll
        for (int r = 0; r < 4; r++) o[r] = (_Float16)(acc[mt][nt][r] + bb[r]);
        *reinterpret_cast<f16x4*>(Out + (long long)n * 128 + mt * 16 + quad * 4) = o;
      }
    }
  }
}

// ---- fused: agg2 zeroing + permute + H1s/H1d GEMMs (one launch) ----
__global__ __launch_bounds__(256, 2)
void h1p_kernel(const _Float16* __restrict__ hf, const float* __restrict__ b1,
                const _Float16* __restrict__ w1st, const _Float16* __restrict__ w1dt,
                _Float16* __restrict__ H1s, _Float16* __restrict__ H1d,
                const int* __restrict__ ei, int* __restrict__ cursor,
                int2* __restrict__ pairs, float* __restrict__ agg2)
{
  int bx = blockIdx.x;
  if (bx < NB_ZERO) {   // zero agg2: 6250 * 256 * 16B = 25.6MB
    reinterpret_cast<f32x4*>(agg2)[bx * 256 + threadIdx.x] = (f32x4){0.f, 0.f, 0.f, 0.f};
    return;
  }
  bx -= NB_ZERO;
  if (bx < NB_PERM) {   // permute: NE = NB_PERM*256 exactly
    int e = bx * 256 + threadIdx.x;
    int s = ei[e], d = ei[NE + e];
    int pos = atomicAdd(&cursor[d], 1);
    pairs[pos] = make_int2(s, d);
    return;
  }
  bx -= NB_PERM;
  const int by = bx & 1;          // 0 -> H1s, 1 -> H1d
  const int bxx = bx >> 1;        // 0..NB_H1-1
  const int t = threadIdx.x;
  const int lane = t & 63, wave = t >> 6;
  const int quad = lane >> 4, l15 = lane & 15;
  const int nbase = bxx * 256 + wave * 64;
  int nid[4];
#pragma unroll
  for (int nt = 0; nt < 4; nt++) {
    int n = nbase + nt * 16 + l15;
    nid[nt] = n < NV ? n : NV - 1;
  }
  if (by == 0) gemm128_rows(hf, nid, w1st, nullptr, H1s, nbase, l15, quad);
  else         gemm128_rows(hf, nid, w1dt, b1,      H1d, nbase, l15, quad);
}

// ============ edge kernel: 128 edges / 2 waves, 3-barrier r1 skeleton ============
// Register-budget fix: r8 had acc[4][8]=128 AGPR + 128 VGPR = 256 unified =
// exactly the 2-waves/SIMD cap -> w2t B-frags loaded just-in-time (1 in
// flight, ~200cy L2 latency exposed per 4-MFMA batch). Split P2 into two
// ft-halves (acc[4][4]=64 AGPR, each half stored to M2t immediately — NO new
// barriers, P3 untouched) and batch-load B8[4] per k-slice with the freed
// regs. s_setprio(1) around MFMA clusters (independent phase-staggered
// blocks — the m191 regime where it pays).
__global__ __launch_bounds__(128, 2)
void edge_kernel(const _Float16* __restrict__ H1s, const _Float16* __restrict__ H1d,
                 const int2* __restrict__ pairs,
                 const _Float16* __restrict__ w2t, const float* __restrict__ b2,
                 float* __restrict__ agg2)
{
  __shared__ __align__(16) _Float16 M2t[128 * 128];   // [feature][edge] swizzled
  __shared__ int sdst[128];
  __shared__ int segdst[128];
  __shared__ __align__(8) unsigned char sseg8[128];
  __shared__ unsigned long long wmask[2];
  __shared__ int snbr[2];

  const int t = threadIdx.x;
  const int lane = t & 63, wave = t >> 6;
  const int quad = lane >> 4, l15 = lane & 15;
  const int ebase = blockIdx.x * 128;
  const int wbase = wave * 64;

  { int2 pr = pairs[ebase + t]; sdst[t] = pr.y; }
  if (t == 0) snbr[0] = (ebase > 0) ? pairs[ebase - 1].y : -1;
  if (t == 1) snbr[1] = (ebase + 128 < NE) ? pairs[ebase + 128].y : -1;

  int esrc[4], edst[4];
#pragma unroll
  for (int et = 0; et < 4; et++) {
    int2 pr = pairs[ebase + wbase + et * 16 + l15];
    esrc[et] = pr.x; edst[et] = pr.y;
  }

  // ---- P1: m1 fragments (A-layout: row=edge(l15), k=quad*8..) ----
  f16x8 m1f[4][4];
#pragma unroll
  for (int et = 0; et < 4; et++) {
#pragma unroll
    for (int s = 0; s < 4; s++) {
      f16x8 a = *reinterpret_cast<const f16x8*>(H1s + (long long)esrc[et] * 128 + s * 32 + quad * 8);
      f16x8 b = *reinterpret_cast<const f16x8*>(H1d + (long long)edst[et] * 128 + s * 32 + quad * 8);
      f16x8 o = a + b;
#pragma unroll
      for (int j = 0; j < 8; j++) o[j] = o[j] > (_Float16)0 ? o[j] : (_Float16)0;
      m1f[et][s] = o;
    }
  }

  // ---- segment ids: one ballot + popcount per wave ----
  __syncthreads();                       // sdst visible
  {
    bool flag = (t > 0) && (sdst[t] != sdst[t - 1]);
    unsigned long long bm = __ballot(flag);
    if (lane == 0) wmask[wave] = bm;
    int pre = __popcll(bm & ((1ull << lane) - 1ull)) + (flag ? 1 : 0);
    __syncthreads();                     // wmask visible
    int sid = pre + (wave ? (int)__popcll(wmask[0]) : 0);
    sseg8[t] = (unsigned char)sid;
    if (flag || t == 0) segdst[sid] = sdst[t];
  }

  // ---- P2: m2^T = relu(m1 @ W2 + b2), two ft-halves (64-AGPR acc each) ----
#pragma unroll
  for (int hf8 = 0; hf8 < 2; hf8++) {
    f32x4 acc[4][4];
#pragma unroll
    for (int et = 0; et < 4; et++)
#pragma unroll
      for (int ft = 0; ft < 4; ft++)
        acc[et][ft] = (f32x4){0.f, 0.f, 0.f, 0.f};

#pragma unroll
    for (int s = 0; s < 4; s++) {
      const int k = s * 32 + quad * 8;
      f16x8 B8[4];
#pragma unroll
      for (int ft = 0; ft < 4; ft++)
        B8[ft] = *reinterpret_cast<const f16x8*>(w2t + ((hf8 * 4 + ft) * 16 + l15) * 128 + k);
      __builtin_amdgcn_s_setprio(1);
#pragma unroll
      for (int ft = 0; ft < 4; ft++)
#pragma unroll
        for (int et = 0; et < 4; et++)
          acc[et][ft] = mfma16(m1f[et][s], B8[ft], acc[et][ft]);
      __builtin_amdgcn_s_setprio(0);
    }
    // epilogue (this half): C row = edge (quad*4+r), col = feature (l15)
#pragma unroll
    for (int ft = 0; ft < 4; ft++) {
      const float bv = b2[(hf8 * 4 + ft) * 16 + l15];
      const int f = (hf8 * 4 + ft) * 16 + l15;
#pragma unroll
      for (int et = 0; et < 4; et++) {
        const int g = wave * 16 + et * 4 + quad;        // edge granule (4 f16)
        f16x4 o;
#pragma unroll
        for (int r = 0; r < 4; r++) {
          float x = acc[et][ft][r] + bv;
          o[r] = (_Float16)(x > 0.f ? x : 0.f);
        }
        *reinterpret_cast<f16x4*>(&M2t[f * 128 + ((g ^ (l15 << 1)) * 4)]) = o;
      }
    }
  }
  __syncthreads();   // M2t + sseg8 + segdst ready

  // ---- P3: agg_seg = S @ M2t via MFMA ----
  const int nseg = (int)__popcll(wmask[0]) + (int)__popcll(wmask[1]) + 1;
  const int nmt = (nseg + 15) >> 4;
  const bool openL = (sdst[0] == snbr[0]);
  const bool openR = (sdst[127] == snbr[1]);

  // hoist B-frags: this wave's feature quarter (ft = wave*4 + 0..3), all K
  f16x8 Bf[4][4];
#pragma unroll
  for (int fl = 0; fl < 4; fl++) {
    const int f = (wave * 4 + fl) * 16 + l15;
#pragma unroll
    for (int s = 0; s < 4; s++) {
      const int g0 = s * 8 + quad * 2;                // 2 granules = 8 edges
      Bf[fl][s] = *reinterpret_cast<const f16x8*>(&M2t[f * 128 + ((g0 ^ (l15 << 1)) * 4)]);
    }
  }
  unsigned long long segb[4];
#pragma unroll
  for (int s = 0; s < 4; s++)
    segb[s] = *reinterpret_cast<const unsigned long long*>(&sseg8[s * 32 + quad * 8]);

  for (int mt = 0; mt < nmt; mt++) {
    const int myseg = mt * 16 + l15;
    f32x4 racc[4];
#pragma unroll
    for (int fl = 0; fl < 4; fl++) racc[fl] = (f32x4){0.f, 0.f, 0.f, 0.f};
#pragma unroll
    for (int s = 0; s < 4; s++) {
      f16x8 S;
#pragma unroll
      for (int j = 0; j < 8; j++)
        S[j] = ((int)((segb[s] >> (8 * j)) & 255ull) == myseg) ? (_Float16)1 : (_Float16)0;
      __builtin_amdgcn_s_setprio(1);
#pragma unroll
      for (int fl = 0; fl < 4; fl++)
        racc[fl] = mfma16(S, Bf[fl][s], racc[fl]);
      __builtin_amdgcn_s_setprio(0);
    }
#pragma unroll
    for (int fl = 0; fl < 4; fl++) {
      const int f = (wave * 4 + fl) * 16 + l15;
#pragma unroll
      for (int r = 0; r < 4; r++) {
        const int sg = mt * 16 + quad * 4 + r;
        if (sg < nseg) {
          float v = racc[fl][r];
          float* p = agg2 + (long long)segdst[sg] * 128 + f;
          const bool at = (sg == 0 && openL) || (sg == nseg - 1 && openR);
          if (at) unsafeAtomicAdd(p, v); else *p = v;
        }
      }
    }
  }
}

// ============ node kernel: x1 = relu(h@Wn1top + agg2@W3n + bn1 + cnt*b3n); out = x1@Wn2 + bn2 ============
__global__ __launch_bounds__(256, 2)
void node_kernel(const _Float16* __restrict__ hf, const float* __restrict__ agg2,
                 const int* __restrict__ counts,
                 const _Float16* __restrict__ wn1c, const float* __restrict__ bn1,
                 const float* __restrict__ b3n,
                 const _Float16* __restrict__ wn2t, const float* __restrict__ bn2,
                 float* __restrict__ out)
{
  __shared__ __align__(16) _Float16 M[256 * 128];
  const int t = threadIdx.x;
  const int lane = t & 63, wave = t >> 6;
  const int quad = lane >> 4, l15 = lane & 15;
  const int wbase = wave * 64;
  const int nbase = blockIdx.x * 256 + wbase;

  int nid[4]; float fcnt[4];
#pragma unroll
  for (int nt = 0; nt < 4; nt++) {
    int n = nbase + nt * 16 + l15;
    nid[nt] = n < NV ? n : NV - 1;
    fcnt[nt] = (n < NV) ? (float)counts[n] : 0.f;   // in-degree = counts (no scan diff)
  }

  f32x4 acc[8][4];
#pragma unroll
  for (int mt = 0; mt < 8; mt++)
#pragma unroll
    for (int nt = 0; nt < 4; nt++)
      acc[mt][nt] = (f32x4){0.f, 0.f, 0.f, 0.f};

  // ---- layer 1: K=256 over [hf | agg2]; B dbuf ----
  f16x8 Bc[4], Bn[4];
#pragma unroll
  for (int nt = 0; nt < 4; nt++)
    Bc[nt] = *reinterpret_cast<const f16x8*>(hf + (long long)nid[nt] * 128 + quad * 8);
#pragma unroll
  for (int s = 0; s < 8; s++) {
    if (s < 7) {
      const int sn = s + 1;
      if (sn < 4) {
#pragma unroll
        for (int nt = 0; nt < 4; nt++)
          Bn[nt] = *reinterpret_cast<const f16x8*>(hf + (long long)nid[nt] * 128 + sn * 32 + quad * 8);
      } else {
#pragma unroll
        for (int nt = 0; nt < 4; nt++) {
          const float* ap = agg2 + (long long)nid[nt] * 128 + (sn - 4) * 32 + quad * 8;
          f32x4 a0 = *reinterpret_cast<const f32x4*>(ap);
          f32x4 a1 = *reinterpret_cast<const f32x4*>(ap + 4);
          f16x8 bb;
#pragma unroll
          for (int j = 0; j < 4; j++) { bb[j] = (_Float16)a0[j]; bb[4 + j] = (_Float16)a1[j]; }
          Bn[nt] = bb;
        }
      }
    }
    const int k = s * 32 + quad * 8;
#pragma unroll
    for (int mt = 0; mt < 8; mt++) {
      f16x8 A = *reinterpret_cast<const f16x8*>(wn1c + (mt * 16 + l15) * 256 + k);
#pragma unroll
      for (int nt = 0; nt < 4; nt++)
        acc[mt][nt] = mfma16(A, Bc[nt], acc[mt][nt]);
    }
#pragma unroll
    for (int nt = 0; nt < 4; nt++) Bc[nt] = Bn[nt];
  }
  // epi: + bn1 + cnt*b3n, relu -> wave-private LDS rows
#pragma unroll
  for (int mt = 0; mt < 8; mt++) {
    f32x4 bb  = *reinterpret_cast<const f32x4*>(bn1 + mt * 16 + quad * 4);
    f32x4 b3c = *reinterpret_cast<const f32x4*>(b3n + mt * 16 + quad * 4);
    const int cbase = 2 * mt + (quad >> 1);
#pragma unroll
    for (int nt = 0; nt < 4; nt++) {
      int row = wbase + nt * 16 + l15;
      int c = cbase ^ (row & 15);
      f16x4 o;
#pragma unroll
      for (int r = 0; r < 4; r++) {
        float x = acc[mt][nt][r] + bb[r] + fcnt[nt] * b3c[r];
        o[r] = (_Float16)(x > 0.f ? x : 0.f);
      }
      *reinterpret_cast<f16x4*>(&M[row * 128 + c * 8 + (quad & 1) * 4]) = o;
      acc[mt][nt] = (f32x4){0.f, 0.f, 0.f, 0.f};
    }
  }

  // ---- layer 2: K=128 from LDS (wave-private rows, no barrier) ----
#pragma unroll
  for (int s = 0; s < 4; s++) {
    f16x8 B[4];
#pragma unroll
    for (int nt = 0; nt < 4; nt++) {
      int row = wbase + nt * 16 + l15;
      B[nt] = *reinterpret_cast<const f16x8*>(&M[row * 128 + (((4 * s + quad) ^ (row & 15)) * 8)]);
    }
    const int k = s * 32 + quad * 8;
#pragma unroll
    for (int mt = 0; mt < 8; mt++) {
      f16x8 A = *reinterpret_cast<const f16x8*>(wn2t + (mt * 16 + l15) * 128 + k);
#pragma unroll
      for (int nt = 0; nt < 4; nt++)
        acc[mt][nt] = mfma16(A, B[nt], acc[mt][nt]);
    }
  }
#pragma unroll
  for (int mt = 0; mt < 8; mt++) {
    f32x4 bias = *reinterpret_cast<const f32x4*>(bn2 + mt * 16 + quad * 4);
#pragma unroll
    for (int nt = 0; nt < 4; nt++) {
      int n = nbase + nt * 16 + l15;
      if (n < NV) {
        f32x4 v;
#pragma unroll
        for (int r = 0; r < 4; r++) v[r] = acc[mt][nt][r] + bias[r];
        *reinterpret_cast<f32x4*>(out + (long long)n * 128 + mt * 16 + quad * 4) = v;
      }
    }
  }
}

static inline size_t align16(size_t x) { return (x + 15) & ~(size_t)15; }

extern "C" void kernel_launch(void* const* d_in, const int* in_sizes, int n_in,
                              void* d_out, int out_size, void* d_ws, size_t ws_size,
                              hipStream_t stream)
{
  const float* h   = (const float*)d_in[0];
  const int*   ei  = (const int*)d_in[1];
  const float* W1  = (const float*)d_in[2];
  const float* b1  = (const float*)d_in[3];
  const float* W2  = (const float*)d_in[4];
  const float* b2  = (const float*)d_in[5];
  const float* W3  = (const float*)d_in[6];
  const float* b3  = (const float*)d_in[7];
  const float* Wn1 = (const float*)d_in[8];
  const float* bn1 = (const float*)d_in[9];
  const float* Wn2 = (const float*)d_in[10];
  const float* bn2 = (const float*)d_in[11];
  float* out = (float*)d_out;

  char* p = (char*)d_ws;
  _Float16* hf   = (_Float16*)p; p += align16((size_t)NV * 128 * 2);
  _Float16* H1s  = (_Float16*)p; p += align16((size_t)NV * 128 * 2);
  _Float16* H1d  = (_Float16*)p; p += align16((size_t)NV * 128 * 2);
  _Float16* w1st = (_Float16*)p; p += align16(128 * 128 * 2);
  _Float16* w1dt = (_Float16*)p; p += align16(128 * 128 * 2);
  _Float16* w2t  = (_Float16*)p; p += align16(128 * 128 * 2);
  _Float16* wn1c = (_Float16*)p; p += align16(128 * 256 * 2);
  _Float16* wn2t = (_Float16*)p; p += align16(128 * 128 * 2);
  float*  b3n  = (float*)p;  p += align16(128 * 4);
  int* counts  = (int*)p; p += align16((size_t)NV * 4);
  int* offsets = (int*)p; p += align16((size_t)(NV + 1) * 4);
  int* cursor  = (int*)p; p += align16((size_t)NV * 4);
  int* bsum    = (int*)p; p += align16((size_t)(NB1 + 1) * 4);
  int2* pairs  = (int2*)p; p += align16((size_t)NE * 8);
  float* agg2  = (float*)p; p += align16((size_t)NV * 128 * 4);

  hipMemsetAsync(counts, 0, (size_t)NV * 4, stream);
  {
    int total = CVT_N + TR_N + W3N_N + B3N_N + NE;
    prep_kernel<<<(total + 255) / 256, 256, 0, stream>>>(
        h, hf, W1, W2, W3, Wn1, Wn2, b3,
        w1st, w1dt, w2t, wn1c, wn2t, b3n, ei, counts);
  }
  bsum_kernel<<<NB1, 1024, 0, stream>>>(counts, bsum);
  offs_kernel<<<NB1, 1024, 0, stream>>>(counts, bsum, offsets, cursor);
  h1p_kernel<<<NB_ZERO + NB_PERM + 2 * NB_H1, 256, 0, stream>>>(
      hf, b1, w1st, w1dt, H1s, H1d, ei, cursor, pairs, agg2);
  edge_kernel<<<NE / 128, 128, 0, stream>>>(H1s, H1d, pairs, w2t, b2, agg2);
  node_kernel<<<(NV + 255) / 256, 256, 0, stream>>>(hf, agg2, counts, wn1c, bn1, b3n,
                                                    wn2t, bn2, out);
}

// Round 11
// 350.856 us; speedup vs baseline: 1.0022x; 1.0022x over previous
//
#include <hip/hip_runtime.h>

#define NV 50000
#define NE 800000
#define CVT_N 1600000
#define TR_N  81920
#define W3N_N 16384
#define B3N_N 128
#define NB1 49        // ceil(NV/1024)
#define NB_ZERO 6250  // agg2 zeroing blocks (25.6MB / (256 thr * 16B))
#define NB_PERM 3125  // NE/256
#define NB_H1 196     // ceil(NV/256)

typedef _Float16 f16x8 __attribute__((ext_vector_type(8)));
typedef _Float16 f16x4 __attribute__((ext_vector_type(4)));
typedef float    f32x4 __attribute__((ext_vector_type(4)));

static __device__ __forceinline__ f32x4 mfma16(f16x8 a, f16x8 b, f32x4 c) {
  return __builtin_amdgcn_mfma_f32_16x16x32_f16(a, b, c, 0, 0, 0);
}

// ---- fused prep: h->f16, 5 128x128 transposes (f16), W3n fold, b3n, hist ----
__global__ void prep_kernel(const float* __restrict__ h, _Float16* __restrict__ hf,
    const float* __restrict__ W1, const float* __restrict__ W2, const float* __restrict__ W3,
    const float* __restrict__ Wn1, const float* __restrict__ Wn2, const float* __restrict__ b3,
    _Float16* __restrict__ w1st, _Float16* __restrict__ w1dt, _Float16* __restrict__ w2t,
    _Float16* __restrict__ wn1c, _Float16* __restrict__ wn2t, float* __restrict__ b3n,
    const int* __restrict__ ei, int* __restrict__ counts)
{
  int i = blockIdx.x * blockDim.x + threadIdx.x;
  if (i < CVT_N) {
    f32x4 v = reinterpret_cast<const f32x4*>(h)[i];
    f16x4 o;
    o[0] = (_Float16)v[0]; o[1] = (_Float16)v[1]; o[2] = (_Float16)v[2]; o[3] = (_Float16)v[3];
    reinterpret_cast<f16x4*>(hf)[i] = o;
    return;
  }
  i -= CVT_N;
  if (i < TR_N) {
    int seg = i >> 14;
    int j = i & 16383;
    int f = j >> 7, k = j & 127;
    switch (seg) {
      case 0: w1st[j] = (_Float16)W1[k * 128 + f]; break;         // W1top^T
      case 1: w1dt[j] = (_Float16)W1[(k + 128) * 128 + f]; break; // W1bot^T
      case 2: w2t[j]  = (_Float16)W2[k * 128 + f]; break;
      case 3: wn1c[f * 256 + k] = (_Float16)Wn1[k * 128 + f]; break;
      case 4: wn2t[j] = (_Float16)Wn2[k * 128 + f]; break;
    }
    return;
  }
  i -= TR_N;
  if (i < W3N_N) {   // wn1c[f][128+ii] = sum_j W3[ii][j] * Wn1[128+j][f]
    int f = i >> 7, ii = i & 127;
    float a = 0.f;
    for (int j = 0; j < 128; j++) a += W3[ii * 128 + j] * Wn1[(128 + j) * 128 + f];
    wn1c[f * 256 + 128 + ii] = (_Float16)a;
    return;
  }
  i -= W3N_N;
  if (i < B3N_N) {
    float a = 0.f;
    for (int j = 0; j < 128; j++) a += b3[j] * Wn1[(128 + j) * 128 + i];
    b3n[i] = a;
    return;
  }
  i -= B3N_N;
  if (i < NE) atomicAdd(&counts[ei[NE + i]], 1);
}

// ---- block sums ----
__global__ __launch_bounds__(1024)
void bsum_kernel(const int* __restrict__ counts, int* __restrict__ bsum) {
  __shared__ int red[1024];
  const int t = threadIdx.x;
  int i = blockIdx.x * 1024 + t;
  red[t] = (i < NV) ? counts[i] : 0;
  __syncthreads();
  for (int off = 512; off > 0; off >>= 1) {
    if (t < off) red[t] += red[t + off];
    __syncthreads();
  }
  if (t == 0) bsum[blockIdx.x] = red[0];
}

// ---- cursor init: block-local scan + inline base (butterfly over 49 block sums) ----
__global__ __launch_bounds__(1024)
void offs_kernel(const int* __restrict__ counts, const int* __restrict__ bsum,
                 int* __restrict__ cursor) {
  __shared__ int s[1024];
  __shared__ int sbase;
  const int t = threadIdx.x;
  int i = blockIdx.x * 1024 + t;
  int v = (i < NV) ? counts[i] : 0;
  s[t] = v;
  if (t < 64) {
    int x = (t < blockIdx.x) ? bsum[t] : 0;   // NB1=49 <= 64
    for (int off = 1; off < 64; off <<= 1) x += __shfl_xor(x, off);
    if (t == 0) sbase = x;
  }
  __syncthreads();
  for (int off = 1; off < 1024; off <<= 1) {
    int x = (t >= off) ? s[t - off] : 0;
    __syncthreads();
    s[t] += x;
    __syncthreads();
  }
  if (i < NV) cursor[i] = sbase + s[t] - v;
}

// ---- one K=128 GEMM (64 rows x 128 feats per wave), f16 ----
static __device__ __forceinline__ void gemm128_rows(
    const _Float16* __restrict__ hf, const int* nid, const _Float16* __restrict__ At,
    const float* __restrict__ bias, _Float16* __restrict__ Out,
    int nbase, int l15, int quad)
{
  f32x4 acc[8][4];
#pragma unroll
  for (int mt = 0; mt < 8; mt++)
#pragma unroll
    for (int nt = 0; nt < 4; nt++)
      acc[mt][nt] = (f32x4){0.f, 0.f, 0.f, 0.f};

  f16x8 Bc[4], Bn[4];
#pragma unroll
  for (int nt = 0; nt < 4; nt++)
    Bc[nt] = *reinterpret_cast<const f16x8*>(hf + (long long)nid[nt] * 128 + quad * 8);
#pragma unroll
  for (int s = 0; s < 4; s++) {
    if (s < 3) {
#pragma unroll
      for (int nt = 0; nt < 4; nt++)
        Bn[nt] = *reinterpret_cast<const f16x8*>(hf + (long long)nid[nt] * 128 + (s + 1) * 32 + quad * 8);
    }
    const int k = s * 32 + quad * 8;
#pragma unroll
    for (int mt = 0; mt < 8; mt++) {
      f16x8 A = *reinterpret_cast<const f16x8*>(At + (mt * 16 + l15) * 128 + k);
#pragma unroll
      for (int nt = 0; nt < 4; nt++)
        acc[mt][nt] = mfma16(A, Bc[nt], acc[mt][nt]);
    }
#pragma unroll
    for (int nt = 0; nt < 4; nt++) Bc[nt] = Bn[nt];
  }
#pragma unroll
  for (int mt = 0; mt < 8; mt++) {
    f32x4 bb = bias ? *reinterpret_cast<const f32x4*>(bias + mt * 16 + quad * 4)
                    : (f32x4){0.f, 0.f, 0.f, 0.f};
#pragma unroll
    for (int nt = 0; nt < 4; nt++) {
      int n = nbase + nt * 16 + l15;
      if (n < NV) {
        f16x4 o;
#pragma unroll
        for (int r = 0; r < 4; r++) o[r] = (_Float16)(acc[mt][nt][r] + bb[r]);
        *reinterpret_cast<f16x4*>(Out + (long long)n * 128 + mt * 16 + quad * 4) = o;
      }
    }
  }
}

// ---- fused: agg2 zeroing + permute + H1s/H1d GEMMs (one launch) ----
__global__ __launch_bounds__(256, 2)
void h1p_kernel(const _Float16* __restrict__ hf, const float* __restrict__ b1,
                const _Float16* __restrict__ w1st, const _Float16* __restrict__ w1dt,
                _Float16* __restrict__ H1s, _Float16* __restrict__ H1d,
                const int* __restrict__ ei, int* __restrict__ cursor,
                int2* __restrict__ pairs, float* __restrict__ agg2)
{
  int bx = blockIdx.x;
  if (bx < NB_ZERO) {   // zero agg2: 6250 * 256 * 16B = 25.6MB
    reinterpret_cast<f32x4*>(agg2)[bx * 256 + threadIdx.x] = (f32x4){0.f, 0.f, 0.f, 0.f};
    return;
  }
  bx -= NB_ZERO;
  if (bx < NB_PERM) {   // permute: NE = NB_PERM*256 exactly
    int e = bx * 256 + threadIdx.x;
    int s = ei[e], d = ei[NE + e];
    int pos = atomicAdd(&cursor[d], 1);
    pairs[pos] = make_int2(s, d);
    return;
  }
  bx -= NB_PERM;
  const int by = bx & 1;          // 0 -> H1s, 1 -> H1d
  const int bxx = bx >> 1;        // 0..NB_H1-1
  const int t = threadIdx.x;
  const int lane = t & 63, wave = t >> 6;
  const int quad = lane >> 4, l15 = lane & 15;
  const int nbase = bxx * 256 + wave * 64;
  int nid[4];
#pragma unroll
  for (int nt = 0; nt < 4; nt++) {
    int n = nbase + nt * 16 + l15;
    nid[nt] = n < NV ? n : NV - 1;
  }
  if (by == 0) gemm128_rows(hf, nid, w1st, nullptr, H1s, nbase, l15, quad);
  else         gemm128_rows(hf, nid, w1dt, b1,      H1d, nbase, l15, quad);
}

// ============ edge kernel: 128 edges / 2 waves — r8/r1 98.5us version, verbatim ============
// Six structural variants (2-pass split, 4-wave, LDS dst-staging, barrier-free,
// reg-split+setprio) all lost to this. Occupancy is LDS-pinned (34KB -> 4
// blocks/CU); barriers provide load-bearing phase interleave at 8 waves/CU;
// acc[4][8]=128 AGPR + 128 VGPR = 256 unified is fully used per wave.
__global__ __launch_bounds__(128, 2)
void edge_kernel(const _Float16* __restrict__ H1s, const _Float16* __restrict__ H1d,
                 const int2* __restrict__ pairs,
                 const _Float16* __restrict__ w2t, const float* __restrict__ b2,
                 float* __restrict__ agg2)
{
  __shared__ __align__(16) _Float16 M2t[128 * 128];   // [feature][edge] swizzled
  __shared__ int sdst[128];
  __shared__ int segdst[128];
  __shared__ __align__(8) unsigned char sseg8[128];
  __shared__ unsigned long long wmask[2];
  __shared__ int snbr[2];

  const int t = threadIdx.x;
  const int lane = t & 63, wave = t >> 6;
  const int quad = lane >> 4, l15 = lane & 15;
  const int ebase = blockIdx.x * 128;
  const int wbase = wave * 64;

  { int2 pr = pairs[ebase + t]; sdst[t] = pr.y; }
  if (t == 0) snbr[0] = (ebase > 0) ? pairs[ebase - 1].y : -1;
  if (t == 1) snbr[1] = (ebase + 128 < NE) ? pairs[ebase + 128].y : -1;

  int esrc[4], edst[4];
#pragma unroll
  for (int et = 0; et < 4; et++) {
    int2 pr = pairs[ebase + wbase + et * 16 + l15];
    esrc[et] = pr.x; edst[et] = pr.y;
  }

  // ---- P1: m1 fragments (A-layout: row=edge(l15), k=quad*8..) ----
  f16x8 m1f[4][4];
#pragma unroll
  for (int et = 0; et < 4; et++) {
#pragma unroll
    for (int s = 0; s < 4; s++) {
      f16x8 a = *reinterpret_cast<const f16x8*>(H1s + (long long)esrc[et] * 128 + s * 32 + quad * 8);
      f16x8 b = *reinterpret_cast<const f16x8*>(H1d + (long long)edst[et] * 128 + s * 32 + quad * 8);
      f16x8 o = a + b;
#pragma unroll
      for (int j = 0; j < 8; j++) o[j] = o[j] > (_Float16)0 ? o[j] : (_Float16)0;
      m1f[et][s] = o;
    }
  }

  // ---- segment ids: one ballot + popcount per wave ----
  __syncthreads();                       // sdst visible
  {
    bool flag = (t > 0) && (sdst[t] != sdst[t - 1]);
    unsigned long long bm = __ballot(flag);
    if (lane == 0) wmask[wave] = bm;
    int pre = __popcll(bm & ((1ull << lane) - 1ull)) + (flag ? 1 : 0);
    __syncthreads();                     // wmask visible
    int sid = pre + (wave ? (int)__popcll(wmask[0]) : 0);
    sseg8[t] = (unsigned char)sid;
    if (flag || t == 0) segdst[sid] = sdst[t];
  }

  // ---- P2: m2^T = relu(m1 @ W2 + b2), stored [feature][edge] ----
  float b2v[8];
#pragma unroll
  for (int ft = 0; ft < 8; ft++) b2v[ft] = b2[ft * 16 + l15];

  f32x4 acc[4][8];
#pragma unroll
  for (int et = 0; et < 4; et++)
#pragma unroll
    for (int ft = 0; ft < 8; ft++)
      acc[et][ft] = (f32x4){0.f, 0.f, 0.f, 0.f};

#pragma unroll
  for (int s = 0; s < 4; s++) {
    const int k = s * 32 + quad * 8;
#pragma unroll
    for (int ft = 0; ft < 8; ft++) {
      f16x8 B = *reinterpret_cast<const f16x8*>(w2t + (ft * 16 + l15) * 128 + k);
#pragma unroll
      for (int et = 0; et < 4; et++)
        acc[et][ft] = mfma16(m1f[et][s], B, acc[et][ft]);
    }
  }
  // epilogue: C row = edge (quad*4+r), col = feature (l15). 8B granule store.
#pragma unroll
  for (int et = 0; et < 4; et++) {
    const int g = wave * 16 + et * 4 + quad;          // edge granule (4 f16)
#pragma unroll
    for (int ft = 0; ft < 8; ft++) {
      const int f = ft * 16 + l15;
      f16x4 o;
#pragma unroll
      for (int r = 0; r < 4; r++) {
        float x = acc[et][ft][r] + b2v[ft];
        o[r] = (_Float16)(x > 0.f ? x : 0.f);
      }
      *reinterpret_cast<f16x4*>(&M2t[f * 128 + ((g ^ (l15 << 1)) * 4)]) = o;
    }
  }
  __syncthreads();   // M2t + sseg8 + segdst ready

  // ---- P3: agg_seg = S @ M2t via MFMA ----
  const int nseg = (int)__popcll(wmask[0]) + (int)__popcll(wmask[1]) + 1;
  const int nmt = (nseg + 15) >> 4;
  const bool openL = (sdst[0] == snbr[0]);
  const bool openR = (sdst[127] == snbr[1]);

  // hoist B-frags: this wave's feature quarter (ft = wave*4 + 0..3), all K
  f16x8 Bf[4][4];
#pragma unroll
  for (int fl = 0; fl < 4; fl++) {
    const int f = (wave * 4 + fl) * 16 + l15;
#pragma unroll
    for (int s = 0; s < 4; s++) {
      const int g0 = s * 8 + quad * 2;                // 2 granules = 8 edges
      Bf[fl][s] = *reinterpret_cast<const f16x8*>(&M2t[f * 128 + ((g0 ^ (l15 << 1)) * 4)]);
    }
  }
  unsigned long long segb[4];
#pragma unroll
  for (int s = 0; s < 4; s++)
    segb[s] = *reinterpret_cast<const unsigned long long*>(&sseg8[s * 32 + quad * 8]);

  for (int mt = 0; mt < nmt; mt++) {
    const int myseg = mt * 16 + l15;
    f32x4 racc[4];
#pragma unroll
    for (int fl = 0; fl < 4; fl++) racc[fl] = (f32x4){0.f, 0.f, 0.f, 0.f};
#pragma unroll
    for (int s = 0; s < 4; s++) {
      f16x8 S;
#pragma unroll
      for (int j = 0; j < 8; j++)
        S[j] = ((int)((segb[s] >> (8 * j)) & 255ull) == myseg) ? (_Float16)1 : (_Float16)0;
#pragma unroll
      for (int fl = 0; fl < 4; fl++)
        racc[fl] = mfma16(S, Bf[fl][s], racc[fl]);
    }
#pragma unroll
    for (int fl = 0; fl < 4; fl++) {
      const int f = (wave * 4 + fl) * 16 + l15;
#pragma unroll
      for (int r = 0; r < 4; r++) {
        const int sg = mt * 16 + quad * 4 + r;
        if (sg < nseg) {
          float v = racc[fl][r];
          float* p = agg2 + (long long)segdst[sg] * 128 + f;
          const bool at = (sg == 0 && openL) || (sg == nseg - 1 && openR);
          if (at) unsafeAtomicAdd(p, v); else *p = v;
        }
      }
    }
  }
}

// ============ node kernel: x1 = relu(h@Wn1top + agg2@W3n + bn1 + cnt*b3n); out = x1@Wn2 + bn2 ============
__global__ __launch_bounds__(256, 2)
void node_kernel(const _Float16* __restrict__ hf, const float* __restrict__ agg2,
                 const int* __restrict__ counts,
                 const _Float16* __restrict__ wn1c, const float* __restrict__ bn1,
                 const float* __restrict__ b3n,
                 const _Float16* __restrict__ wn2t, const float* __restrict__ bn2,
                 float* __restrict__ out)
{
  __shared__ __align__(16) _Float16 M[256 * 128];
  const int t = threadIdx.x;
  const int lane = t & 63, wave = t >> 6;
  const int quad = lane >> 4, l15 = lane & 15;
  const int wbase = wave * 64;
  const int nbase = blockIdx.x * 256 + wbase;

  int nid[4]; float fcnt[4];
#pragma unroll
  for (int nt = 0; nt < 4; nt++) {
    int n = nbase + nt * 16 + l15;
    nid[nt] = n < NV ? n : NV - 1;
    fcnt[nt] = (n < NV) ? (float)counts[n] : 0.f;   // in-degree = counts (no scan diff)
  }

  f32x4 acc[8][4];
#pragma unroll
  for (int mt = 0; mt < 8; mt++)
#pragma unroll
    for (int nt = 0; nt < 4; nt++)
      acc[mt][nt] = (f32x4){0.f, 0.f, 0.f, 0.f};

  // ---- layer 1: K=256 over [hf | agg2]; B dbuf ----
  f16x8 Bc[4], Bn[4];
#pragma unroll
  for (int nt = 0; nt < 4; nt++)
    Bc[nt] = *reinterpret_cast<const f16x8*>(hf + (long long)nid[nt] * 128 + quad * 8);
#pragma unroll
  for (int s = 0; s < 8; s++) {
    if (s < 7) {
      const int sn = s + 1;
      if (sn < 4) {
#pragma unroll
        for (int nt = 0; nt < 4; nt++)
          Bn[nt] = *reinterpret_cast<const f16x8*>(hf + (long long)nid[nt] * 128 + sn * 32 + quad * 8);
      } else {
#pragma unroll
        for (int nt = 0; nt < 4; nt++) {
          const float* ap = agg2 + (long long)nid[nt] * 128 + (sn - 4) * 32 + quad * 8;
          f32x4 a0 = *reinterpret_cast<const f32x4*>(ap);
          f32x4 a1 = *reinterpret_cast<const f32x4*>(ap + 4);
          f16x8 bb;
#pragma unroll
          for (int j = 0; j < 4; j++) { bb[j] = (_Float16)a0[j]; bb[4 + j] = (_Float16)a1[j]; }
          Bn[nt] = bb;
        }
      }
    }
    const int k = s * 32 + quad * 8;
#pragma unroll
    for (int mt = 0; mt < 8; mt++) {
      f16x8 A = *reinterpret_cast<const f16x8*>(wn1c + (mt * 16 + l15) * 256 + k);
#pragma unroll
      for (int nt = 0; nt < 4; nt++)
        acc[mt][nt] = mfma16(A, Bc[nt], acc[mt][nt]);
    }
#pragma unroll
    for (int nt = 0; nt < 4; nt++) Bc[nt] = Bn[nt];
  }
  // epi: + bn1 + cnt*b3n, relu -> wave-private LDS rows
#pragma unroll
  for (int mt = 0; mt < 8; mt++) {
    f32x4 bb  = *reinterpret_cast<const f32x4*>(bn1 + mt * 16 + quad * 4);
    f32x4 b3c = *reinterpret_cast<const f32x4*>(b3n + mt * 16 + quad * 4);
    const int cbase = 2 * mt + (quad >> 1);
#pragma unroll
    for (int nt = 0; nt < 4; nt++) {
      int row = wbase + nt * 16 + l15;
      int c = cbase ^ (row & 15);
      f16x4 o;
#pragma unroll
      for (int r = 0; r < 4; r++) {
        float x = acc[mt][nt][r] + bb[r] + fcnt[nt] * b3c[r];
        o[r] = (_Float16)(x > 0.f ? x : 0.f);
      }
      *reinterpret_cast<f16x4*>(&M[row * 128 + c * 8 + (quad & 1) * 4]) = o;
      acc[mt][nt] = (f32x4){0.f, 0.f, 0.f, 0.f};
    }
  }

  // ---- layer 2: K=128 from LDS (wave-private rows, no barrier) ----
#pragma unroll
  for (int s = 0; s < 4; s++) {
    f16x8 B[4];
#pragma unroll
    for (int nt = 0; nt < 4; nt++) {
      int row = wbase + nt * 16 + l15;
      B[nt] = *reinterpret_cast<const f16x8*>(&M[row * 128 + (((4 * s + quad) ^ (row & 15)) * 8)]);
    }
    const int k = s * 32 + quad * 8;
#pragma unroll
    for (int mt = 0; mt < 8; mt++) {
      f16x8 A = *reinterpret_cast<const f16x8*>(wn2t + (mt * 16 + l15) * 128 + k);
#pragma unroll
      for (int nt = 0; nt < 4; nt++)
        acc[mt][nt] = mfma16(A, B[nt], acc[mt][nt]);
    }
  }
#pragma unroll
  for (int mt = 0; mt < 8; mt++) {
    f32x4 bias = *reinterpret_cast<const f32x4*>(bn2 + mt * 16 + quad * 4);
#pragma unroll
    for (int nt = 0; nt < 4; nt++) {
      int n = nbase + nt * 16 + l15;
      if (n < NV) {
        f32x4 v;
#pragma unroll
        for (int r = 0; r < 4; r++) v[r] = acc[mt][nt][r] + bias[r];
        *reinterpret_cast<f32x4*>(out + (long long)n * 128 + mt * 16 + quad * 4) = v;
      }
    }
  }
}

static inline size_t align16(size_t x) { return (x + 15) & ~(size_t)15; }

extern "C" void kernel_launch(void* const* d_in, const int* in_sizes, int n_in,
                              void* d_out, int out_size, void* d_ws, size_t ws_size,
                              hipStream_t stream)
{
  const float* h   = (const float*)d_in[0];
  const int*   ei  = (const int*)d_in[1];
  const float* W1  = (const float*)d_in[2];
  const float* b1  = (const float*)d_in[3];
  const float* W2  = (const float*)d_in[4];
  const float* b2  = (const float*)d_in[5];
  const float* W3  = (const float*)d_in[6];
  const float* b3  = (const float*)d_in[7];
  const float* Wn1 = (const float*)d_in[8];
  const float* bn1 = (const float*)d_in[9];
  const float* Wn2 = (const float*)d_in[10];
  const float* bn2 = (const float*)d_in[11];
  float* out = (float*)d_out;

  char* p = (char*)d_ws;
  _Float16* hf   = (_Float16*)p; p += align16((size_t)NV * 128 * 2);
  _Float16* H1s  = (_Float16*)p; p += align16((size_t)NV * 128 * 2);
  _Float16* H1d  = (_Float16*)p; p += align16((size_t)NV * 128 * 2);
  _Float16* w1st = (_Float16*)p; p += align16(128 * 128 * 2);
  _Float16* w1dt = (_Float16*)p; p += align16(128 * 128 * 2);
  _Float16* w2t  = (_Float16*)p; p += align16(128 * 128 * 2);
  _Float16* wn1c = (_Float16*)p; p += align16(128 * 256 * 2);
  _Float16* wn2t = (_Float16*)p; p += align16(128 * 128 * 2);
  float*  b3n  = (float*)p;  p += align16(128 * 4);
  int* counts  = (int*)p; p += align16((size_t)NV * 4);
  int* cursor  = (int*)p; p += align16((size_t)NV * 4);
  int* bsum    = (int*)p; p += align16((size_t)(NB1 + 1) * 4);
  int2* pairs  = (int2*)p; p += align16((size_t)NE * 8);
  float* agg2  = (float*)p; p += align16((size_t)NV * 128 * 4);

  hipMemsetAsync(counts, 0, (size_t)NV * 4, stream);
  {
    int total = CVT_N + TR_N + W3N_N + B3N_N + NE;
    prep_kernel<<<(total + 255) / 256, 256, 0, stream>>>(
        h, hf, W1, W2, W3, Wn1, Wn2, b3,
        w1st, w1dt, w2t, wn1c, wn2t, b3n, ei, counts);
  }
  bsum_kernel<<<NB1, 1024, 0, stream>>>(counts, bsum);
  offs_kernel<<<NB1, 1024, 0, stream>>>(counts, bsum, cursor);
  h1p_kernel<<<NB_ZERO + NB_PERM + 2 * NB_H1, 256, 0, stream>>>(
      hf, b1, w1st, w1dt, H1s, H1d, ei, cursor, pairs, agg2);
  edge_kernel<<<NE / 128, 128, 0, stream>>>(H1s, H1d, pairs, w2t, b2, agg2);
  node_kernel<<<(NV + 255) / 256, 256, 0, stream>>>(hf, agg2, counts, wn1c, bn1, b3n,
                                                    wn2t, bn2, out);
}

// Round 12
// 332.331 us; speedup vs baseline: 1.0581x; 1.0557x over previous
//
#include <hip/hip_runtime.h>

#define NV 50000
#define NE 800000
#define CVT_N 1600000
#define TR_N  81920
#define W3N_N 16384
#define B3N_N 128
#define NB1 49        // ceil(NV/1024)
#define NB_ZERO 6250  // agg2 zeroing blocks (25.6MB / (256 thr * 16B))
#define NB_PERM 3125  // NE/256
#define NB_H1 196     // ceil(NV/256)

typedef _Float16 f16x8 __attribute__((ext_vector_type(8)));
typedef _Float16 f16x4 __attribute__((ext_vector_type(4)));
typedef float    f32x4 __attribute__((ext_vector_type(4)));

static __device__ __forceinline__ f32x4 mfma16(f16x8 a, f16x8 b, f32x4 c) {
  return __builtin_amdgcn_mfma_f32_16x16x32_f16(a, b, c, 0, 0, 0);
}

// ---- fused prep: hist FIRST (atomic latency soaks under streaming work),
//      then h->f16 cvt, 5 128x128 transposes (f16), W3n fold, b3n ----
__global__ void prep_kernel(const float* __restrict__ h, _Float16* __restrict__ hf,
    const float* __restrict__ W1, const float* __restrict__ W2, const float* __restrict__ W3,
    const float* __restrict__ Wn1, const float* __restrict__ Wn2, const float* __restrict__ b3,
    _Float16* __restrict__ w1st, _Float16* __restrict__ w1dt, _Float16* __restrict__ w2t,
    _Float16* __restrict__ wn1c, _Float16* __restrict__ wn2t, float* __restrict__ b3n,
    const int* __restrict__ ei, int* __restrict__ counts)
{
  int i = blockIdx.x * blockDim.x + threadIdx.x;
  if (i < NE) {        // histogram first: 800K device atomics start at t=0
    atomicAdd(&counts[ei[NE + i]], 1);
    return;
  }
  i -= NE;
  if (i < CVT_N) {
    f32x4 v = reinterpret_cast<const f32x4*>(h)[i];
    f16x4 o;
    o[0] = (_Float16)v[0]; o[1] = (_Float16)v[1]; o[2] = (_Float16)v[2]; o[3] = (_Float16)v[3];
    reinterpret_cast<f16x4*>(hf)[i] = o;
    return;
  }
  i -= CVT_N;
  if (i < TR_N) {
    int seg = i >> 14;
    int j = i & 16383;
    int f = j >> 7, k = j & 127;
    switch (seg) {
      case 0: w1st[j] = (_Float16)W1[k * 128 + f]; break;         // W1top^T
      case 1: w1dt[j] = (_Float16)W1[(k + 128) * 128 + f]; break; // W1bot^T
      case 2: w2t[j]  = (_Float16)W2[k * 128 + f]; break;
      case 3: wn1c[f * 256 + k] = (_Float16)Wn1[k * 128 + f]; break;
      case 4: wn2t[j] = (_Float16)Wn2[k * 128 + f]; break;
    }
    return;
  }
  i -= TR_N;
  if (i < W3N_N) {   // wn1c[f][128+ii] = sum_j W3[ii][j] * Wn1[128+j][f]
    int f = i >> 7, ii = i & 127;
    float a = 0.f;
    for (int j = 0; j < 128; j++) a += W3[ii * 128 + j] * Wn1[(128 + j) * 128 + f];
    wn1c[f * 256 + 128 + ii] = (_Float16)a;
    return;
  }
  i -= W3N_N;
  if (i < B3N_N) {
    float a = 0.f;
    for (int j = 0; j < 128; j++) a += b3[j] * Wn1[(128 + j) * 128 + i];
    b3n[i] = a;
  }
}

// ---- block sums ----
__global__ __launch_bounds__(1024)
void bsum_kernel(const int* __restrict__ counts, int* __restrict__ bsum) {
  __shared__ int red[1024];
  const int t = threadIdx.x;
  int i = blockIdx.x * 1024 + t;
  red[t] = (i < NV) ? counts[i] : 0;
  __syncthreads();
  for (int off = 512; off > 0; off >>= 1) {
    if (t < off) red[t] += red[t + off];
    __syncthreads();
  }
  if (t == 0) bsum[blockIdx.x] = red[0];
}

// ---- cursor init: block-local scan + inline base (butterfly over 49 block sums) ----
__global__ __launch_bounds__(1024)
void offs_kernel(const int* __restrict__ counts, const int* __restrict__ bsum,
                 int* __restrict__ cursor) {
  __shared__ int s[1024];
  __shared__ int sbase;
  const int t = threadIdx.x;
  int i = blockIdx.x * 1024 + t;
  int v = (i < NV) ? counts[i] : 0;
  s[t] = v;
  if (t < 64) {
    int x = (t < blockIdx.x) ? bsum[t] : 0;   // NB1=49 <= 64
    for (int off = 1; off < 64; off <<= 1) x += __shfl_xor(x, off);
    if (t == 0) sbase = x;
  }
  __syncthreads();
  for (int off = 1; off < 1024; off <<= 1) {
    int x = (t >= off) ? s[t - off] : 0;
    __syncthreads();
    s[t] += x;
    __syncthreads();
  }
  if (i < NV) cursor[i] = sbase + s[t] - v;
}

// ---- one K=128 GEMM (64 rows x 128 feats per wave), f16 ----
static __device__ __forceinline__ void gemm128_rows(
    const _Float16* __restrict__ hf, const int* nid, const _Float16* __restrict__ At,
    const float* __restrict__ bias, _Float16* __restrict__ Out,
    int nbase, int l15, int quad)
{
  f32x4 acc[8][4];
#pragma unroll
  for (int mt = 0; mt < 8; mt++)
#pragma unroll
    for (int nt = 0; nt < 4; nt++)
      acc[mt][nt] = (f32x4){0.f, 0.f, 0.f, 0.f};

  f16x8 Bc[4], Bn[4];
#pragma unroll
  for (int nt = 0; nt < 4; nt++)
    Bc[nt] = *reinterpret_cast<const f16x8*>(hf + (long long)nid[nt] * 128 + quad * 8);
#pragma unroll
  for (int s = 0; s < 4; s++) {
    if (s < 3) {
#pragma unroll
      for (int nt = 0; nt < 4; nt++)
        Bn[nt] = *reinterpret_cast<const f16x8*>(hf + (long long)nid[nt] * 128 + (s + 1) * 32 + quad * 8);
    }
    const int k = s * 32 + quad * 8;
#pragma unroll
    for (int mt = 0; mt < 8; mt++) {
      f16x8 A = *reinterpret_cast<const f16x8*>(At + (mt * 16 + l15) * 128 + k);
#pragma unroll
      for (int nt = 0; nt < 4; nt++)
        acc[mt][nt] = mfma16(A, Bc[nt], acc[mt][nt]);
    }
#pragma unroll
    for (int nt = 0; nt < 4; nt++) Bc[nt] = Bn[nt];
  }
#pragma unroll
  for (int mt = 0; mt < 8; mt++) {
    f32x4 bb = bias ? *reinterpret_cast<const f32x4*>(bias + mt * 16 + quad * 4)
                    : (f32x4){0.f, 0.f, 0.f, 0.f};
#pragma unroll
    for (int nt = 0; nt < 4; nt++) {
      int n = nbase + nt * 16 + l15;
      if (n < NV) {
        f16x4 o;
#pragma unroll
        for (int r = 0; r < 4; r++) o[r] = (_Float16)(acc[mt][nt][r] + bb[r]);
        *reinterpret_cast<f16x4*>(Out + (long long)n * 128 + mt * 16 + quad * 4) = o;
      }
    }
  }
}

// ---- fused: H1 GEMMs FIRST (compute overlaps the atomic/scatter phase),
//      then permute, then agg2 zeroing ----
__global__ __launch_bounds__(256, 2)
void h1p_kernel(const _Float16* __restrict__ hf, const float* __restrict__ b1,
                const _Float16* __restrict__ w1st, const _Float16* __restrict__ w1dt,
                _Float16* __restrict__ H1s, _Float16* __restrict__ H1d,
                const int* __restrict__ ei, int* __restrict__ cursor,
                int2* __restrict__ pairs, float* __restrict__ agg2)
{
  int bx = blockIdx.x;
  if (bx < 2 * NB_H1) {   // H1s/H1d GEMMs: the only compute — dispatch first
    const int by = bx & 1;          // 0 -> H1s, 1 -> H1d
    const int bxx = bx >> 1;        // 0..NB_H1-1
    const int t = threadIdx.x;
    const int lane = t & 63, wave = t >> 6;
    const int quad = lane >> 4, l15 = lane & 15;
    const int nbase = bxx * 256 + wave * 64;
    int nid[4];
#pragma unroll
    for (int nt = 0; nt < 4; nt++) {
      int n = nbase + nt * 16 + l15;
      nid[nt] = n < NV ? n : NV - 1;
    }
    if (by == 0) gemm128_rows(hf, nid, w1st, nullptr, H1s, nbase, l15, quad);
    else         gemm128_rows(hf, nid, w1dt, b1,      H1d, nbase, l15, quad);
    return;
  }
  bx -= 2 * NB_H1;
  if (bx < NB_PERM) {   // permute: NE = NB_PERM*256 exactly
    int e = bx * 256 + threadIdx.x;
    int s = ei[e], d = ei[NE + e];
    int pos = atomicAdd(&cursor[d], 1);
    pairs[pos] = make_int2(s, d);
    return;
  }
  bx -= NB_PERM;
  // zero agg2: 6250 * 256 * 16B = 25.6MB (needed only by edge_kernel)
  reinterpret_cast<f32x4*>(agg2)[bx * 256 + threadIdx.x] = (f32x4){0.f, 0.f, 0.f, 0.f};
}

// ============ edge kernel: 128 edges / 2 waves — r8/r1 98.2us version, verbatim ============
// Six structural variants (2-pass split, 4-wave, LDS dst-staging, barrier-free,
// reg-split+setprio) all lost to this. Occupancy is LDS-pinned (34KB -> 4
// blocks/CU); barriers provide load-bearing phase interleave at 8 waves/CU;
// acc[4][8]=128 AGPR + 128 VGPR = 256 unified is fully used per wave.
__global__ __launch_bounds__(128, 2)
void edge_kernel(const _Float16* __restrict__ H1s, const _Float16* __restrict__ H1d,
                 const int2* __restrict__ pairs,
                 const _Float16* __restrict__ w2t, const float* __restrict__ b2,
                 float* __restrict__ agg2)
{
  __shared__ __align__(16) _Float16 M2t[128 * 128];   // [feature][edge] swizzled
  __shared__ int sdst[128];
  __shared__ int segdst[128];
  __shared__ __align__(8) unsigned char sseg8[128];
  __shared__ unsigned long long wmask[2];
  __shared__ int snbr[2];

  const int t = threadIdx.x;
  const int lane = t & 63, wave = t >> 6;
  const int quad = lane >> 4, l15 = lane & 15;
  const int ebase = blockIdx.x * 128;
  const int wbase = wave * 64;

  { int2 pr = pairs[ebase + t]; sdst[t] = pr.y; }
  if (t == 0) snbr[0] = (ebase > 0) ? pairs[ebase - 1].y : -1;
  if (t == 1) snbr[1] = (ebase + 128 < NE) ? pairs[ebase + 128].y : -1;

  int esrc[4], edst[4];
#pragma unroll
  for (int et = 0; et < 4; et++) {
    int2 pr = pairs[ebase + wbase + et * 16 + l15];
    esrc[et] = pr.x; edst[et] = pr.y;
  }

  // ---- P1: m1 fragments (A-layout: row=edge(l15), k=quad*8..) ----
  f16x8 m1f[4][4];
#pragma unroll
  for (int et = 0; et < 4; et++) {
#pragma unroll
    for (int s = 0; s < 4; s++) {
      f16x8 a = *reinterpret_cast<const f16x8*>(H1s + (long long)esrc[et] * 128 + s * 32 + quad * 8);
      f16x8 b = *reinterpret_cast<const f16x8*>(H1d + (long long)edst[et] * 128 + s * 32 + quad * 8);
      f16x8 o = a + b;
#pragma unroll
      for (int j = 0; j < 8; j++) o[j] = o[j] > (_Float16)0 ? o[j] : (_Float16)0;
      m1f[et][s] = o;
    }
  }

  // ---- segment ids: one ballot + popcount per wave ----
  __syncthreads();                       // sdst visible
  {
    bool flag = (t > 0) && (sdst[t] != sdst[t - 1]);
    unsigned long long bm = __ballot(flag);
    if (lane == 0) wmask[wave] = bm;
    int pre = __popcll(bm & ((1ull << lane) - 1ull)) + (flag ? 1 : 0);
    __syncthreads();                     // wmask visible
    int sid = pre + (wave ? (int)__popcll(wmask[0]) : 0);
    sseg8[t] = (unsigned char)sid;
    if (flag || t == 0) segdst[sid] = sdst[t];
  }

  // ---- P2: m2^T = relu(m1 @ W2 + b2), stored [feature][edge] ----
  float b2v[8];
#pragma unroll
  for (int ft = 0; ft < 8; ft++) b2v[ft] = b2[ft * 16 + l15];

  f32x4 acc[4][8];
#pragma unroll
  for (int et = 0; et < 4; et++)
#pragma unroll
    for (int ft = 0; ft < 8; ft++)
      acc[et][ft] = (f32x4){0.f, 0.f, 0.f, 0.f};

#pragma unroll
  for (int s = 0; s < 4; s++) {
    const int k = s * 32 + quad * 8;
#pragma unroll
    for (int ft = 0; ft < 8; ft++) {
      f16x8 B = *reinterpret_cast<const f16x8*>(w2t + (ft * 16 + l15) * 128 + k);
#pragma unroll
      for (int et = 0; et < 4; et++)
        acc[et][ft] = mfma16(m1f[et][s], B, acc[et][ft]);
    }
  }
  // epilogue: C row = edge (quad*4+r), col = feature (l15). 8B granule store.
#pragma unroll
  for (int et = 0; et < 4; et++) {
    const int g = wave * 16 + et * 4 + quad;          // edge granule (4 f16)
#pragma unroll
    for (int ft = 0; ft < 8; ft++) {
      const int f = ft * 16 + l15;
      f16x4 o;
#pragma unroll
      for (int r = 0; r < 4; r++) {
        float x = acc[et][ft][r] + b2v[ft];
        o[r] = (_Float16)(x > 0.f ? x : 0.f);
      }
      *reinterpret_cast<f16x4*>(&M2t[f * 128 + ((g ^ (l15 << 1)) * 4)]) = o;
    }
  }
  __syncthreads();   // M2t + sseg8 + segdst ready

  // ---- P3: agg_seg = S @ M2t via MFMA ----
  const int nseg = (int)__popcll(wmask[0]) + (int)__popcll(wmask[1]) + 1;
  const int nmt = (nseg + 15) >> 4;
  const bool openL = (sdst[0] == snbr[0]);
  const bool openR = (sdst[127] == snbr[1]);

  // hoist B-frags: this wave's feature quarter (ft = wave*4 + 0..3), all K
  f16x8 Bf[4][4];
#pragma unroll
  for (int fl = 0; fl < 4; fl++) {
    const int f = (wave * 4 + fl) * 16 + l15;
#pragma unroll
    for (int s = 0; s < 4; s++) {
      const int g0 = s * 8 + quad * 2;                // 2 granules = 8 edges
      Bf[fl][s] = *reinterpret_cast<const f16x8*>(&M2t[f * 128 + ((g0 ^ (l15 << 1)) * 4)]);
    }
  }
  unsigned long long segb[4];
#pragma unroll
  for (int s = 0; s < 4; s++)
    segb[s] = *reinterpret_cast<const unsigned long long*>(&sseg8[s * 32 + quad * 8]);

  for (int mt = 0; mt < nmt; mt++) {
    const int myseg = mt * 16 + l15;
    f32x4 racc[4];
#pragma unroll
    for (int fl = 0; fl < 4; fl++) racc[fl] = (f32x4){0.f, 0.f, 0.f, 0.f};
#pragma unroll
    for (int s = 0; s < 4; s++) {
      f16x8 S;
#pragma unroll
      for (int j = 0; j < 8; j++)
        S[j] = ((int)((segb[s] >> (8 * j)) & 255ull) == myseg) ? (_Float16)1 : (_Float16)0;
#pragma unroll
      for (int fl = 0; fl < 4; fl++)
        racc[fl] = mfma16(S, Bf[fl][s], racc[fl]);
    }
#pragma unroll
    for (int fl = 0; fl < 4; fl++) {
      const int f = (wave * 4 + fl) * 16 + l15;
#pragma unroll
      for (int r = 0; r < 4; r++) {
        const int sg = mt * 16 + quad * 4 + r;
        if (sg < nseg) {
          float v = racc[fl][r];
          float* p = agg2 + (long long)segdst[sg] * 128 + f;
          const bool at = (sg == 0 && openL) || (sg == nseg - 1 && openR);
          if (at) unsafeAtomicAdd(p, v); else *p = v;
        }
      }
    }
  }
}

// ============ node kernel: x1 = relu(h@Wn1top + agg2@W3n + bn1 + cnt*b3n); out = x1@Wn2 + bn2 ============
__global__ __launch_bounds__(256, 2)
void node_kernel(const _Float16* __restrict__ hf, const float* __restrict__ agg2,
                 const int* __restrict__ counts,
                 const _Float16* __restrict__ wn1c, const float* __restrict__ bn1,
                 const float* __restrict__ b3n,
                 const _Float16* __restrict__ wn2t, const float* __restrict__ bn2,
                 float* __restrict__ out)
{
  __shared__ __align__(16) _Float16 M[256 * 128];
  const int t = threadIdx.x;
  const int lane = t & 63, wave = t >> 6;
  const int quad = lane >> 4, l15 = lane & 15;
  const int wbase = wave * 64;
  const int nbase = blockIdx.x * 256 + wbase;

  int nid[4]; float fcnt[4];
#pragma unroll
  for (int nt = 0; nt < 4; nt++) {
    int n = nbase + nt * 16 + l15;
    nid[nt] = n < NV ? n : NV - 1;
    fcnt[nt] = (n < NV) ? (float)counts[n] : 0.f;   // in-degree = counts (no scan diff)
  }

  f32x4 acc[8][4];
#pragma unroll
  for (int mt = 0; mt < 8; mt++)
#pragma unroll
    for (int nt = 0; nt < 4; nt++)
      acc[mt][nt] = (f32x4){0.f, 0.f, 0.f, 0.f};

  // ---- layer 1: K=256 over [hf | agg2]; B dbuf ----
  f16x8 Bc[4], Bn[4];
#pragma unroll
  for (int nt = 0; nt < 4; nt++)
    Bc[nt] = *reinterpret_cast<const f16x8*>(hf + (long long)nid[nt] * 128 + quad * 8);
#pragma unroll
  for (int s = 0; s < 8; s++) {
    if (s < 7) {
      const int sn = s + 1;
      if (sn < 4) {
#pragma unroll
        for (int nt = 0; nt < 4; nt++)
          Bn[nt] = *reinterpret_cast<const f16x8*>(hf + (long long)nid[nt] * 128 + sn * 32 + quad * 8);
      } else {
#pragma unroll
        for (int nt = 0; nt < 4; nt++) {
          const float* ap = agg2 + (long long)nid[nt] * 128 + (sn - 4) * 32 + quad * 8;
          f32x4 a0 = *reinterpret_cast<const f32x4*>(ap);
          f32x4 a1 = *reinterpret_cast<const f32x4*>(ap + 4);
          f16x8 bb;
#pragma unroll
          for (int j = 0; j < 4; j++) { bb[j] = (_Float16)a0[j]; bb[4 + j] = (_Float16)a1[j]; }
          Bn[nt] = bb;
        }
      }
    }
    const int k = s * 32 + quad * 8;
#pragma unroll
    for (int mt = 0; mt < 8; mt++) {
      f16x8 A = *reinterpret_cast<const f16x8*>(wn1c + (mt * 16 + l15) * 256 + k);
#pragma unroll
      for (int nt = 0; nt < 4; nt++)
        acc[mt][nt] = mfma16(A, Bc[nt], acc[mt][nt]);
    }
#pragma unroll
    for (int nt = 0; nt < 4; nt++) Bc[nt] = Bn[nt];
  }
  // epi: + bn1 + cnt*b3n, relu -> wave-private LDS rows
#pragma unroll
  for (int mt = 0; mt < 8; mt++) {
    f32x4 bb  = *reinterpret_cast<const f32x4*>(bn1 + mt * 16 + quad * 4);
    f32x4 b3c = *reinterpret_cast<const f32x4*>(b3n + mt * 16 + quad * 4);
    const int cbase = 2 * mt + (quad >> 1);
#pragma unroll
    for (int nt = 0; nt < 4; nt++) {
      int row = wbase + nt * 16 + l15;
      int c = cbase ^ (row & 15);
      f16x4 o;
#pragma unroll
      for (int r = 0; r < 4; r++) {
        float x = acc[mt][nt][r] + bb[r] + fcnt[nt] * b3c[r];
        o[r] = (_Float16)(x > 0.f ? x : 0.f);
      }
      *reinterpret_cast<f16x4*>(&M[row * 128 + c * 8 + (quad & 1) * 4]) = o;
      acc[mt][nt] = (f32x4){0.f, 0.f, 0.f, 0.f};
    }
  }

  // ---- layer 2: K=128 from LDS (wave-private rows, no barrier) ----
#pragma unroll
  for (int s = 0; s < 4; s++) {
    f16x8 B[4];
#pragma unroll
    for (int nt = 0; nt < 4; nt++) {
      int row = wbase + nt * 16 + l15;
      B[nt] = *reinterpret_cast<const f16x8*>(&M[row * 128 + (((4 * s + quad) ^ (row & 15)) * 8)]);
    }
    const int k = s * 32 + quad * 8;
#pragma unroll
    for (int mt = 0; mt < 8; mt++) {
      f16x8 A = *reinterpret_cast<const f16x8*>(wn2t + (mt * 16 + l15) * 128 + k);
#pragma unroll
      for (int nt = 0; nt < 4; nt++)
        acc[mt][nt] = mfma16(A, B[nt], acc[mt][nt]);
    }
  }
#pragma unroll
  for (int mt = 0; mt < 8; mt++) {
    f32x4 bias = *reinterpret_cast<const f32x4*>(bn2 + mt * 16 + quad * 4);
#pragma unroll
    for (int nt = 0; nt < 4; nt++) {
      int n = nbase + nt * 16 + l15;
      if (n < NV) {
        f32x4 v;
#pragma unroll
        for (int r = 0; r < 4; r++) v[r] = acc[mt][nt][r] + bias[r];
        *reinterpret_cast<f32x4*>(out + (long long)n * 128 + mt * 16 + quad * 4) = v;
      }
    }
  }
}

static inline size_t align16(size_t x) { return (x + 15) & ~(size_t)15; }

extern "C" void kernel_launch(void* const* d_in, const int* in_sizes, int n_in,
                              void* d_out, int out_size, void* d_ws, size_t ws_size,
                              hipStream_t stream)
{
  const float* h   = (const float*)d_in[0];
  const int*   ei  = (const int*)d_in[1];
  const float* W1  = (const float*)d_in[2];
  const float* b1  = (const float*)d_in[3];
  const float* W2  = (const float*)d_in[4];
  const float* b2  = (const float*)d_in[5];
  const float* W3  = (const float*)d_in[6];
  const float* b3  = (const float*)d_in[7];
  const float* Wn1 = (const float*)d_in[8];
  const float* bn1 = (const float*)d_in[9];
  const float* Wn2 = (const float*)d_in[10];
  const float* bn2 = (const float*)d_in[11];
  float* out = (float*)d_out;

  char* p = (char*)d_ws;
  _Float16* hf   = (_Float16*)p; p += align16((size_t)NV * 128 * 2);
  _Float16* H1s  = (_Float16*)p; p += align16((size_t)NV * 128 * 2);
  _Float16* H1d  = (_Float16*)p; p += align16((size_t)NV * 128 * 2);
  _Float16* w1st = (_Float16*)p; p += align16(128 * 128 * 2);
  _Float16* w1dt = (_Float16*)p; p += align16(128 * 128 * 2);
  _Float16* w2t  = (_Float16*)p; p += align16(128 * 128 * 2);
  _Float16* wn1c = (_Float16*)p; p += align16(128 * 256 * 2);
  _Float16* wn2t = (_Float16*)p; p += align16(128 * 128 * 2);
  float*  b3n  = (float*)p;  p += align16(128 * 4);
  int* counts  = (int*)p; p += align16((size_t)NV * 4);
  int* cursor  = (int*)p; p += align16((size_t)NV * 4);
  int* bsum    = (int*)p; p += align16((size_t)(NB1 + 1) * 4);
  int2* pairs  = (int2*)p; p += align16((size_t)NE * 8);
  float* agg2  = (float*)p; p += align16((size_t)NV * 128 * 4);

  hipMemsetAsync(counts, 0, (size_t)NV * 4, stream);
  {
    int total = NE + CVT_N + TR_N + W3N_N + B3N_N;
    prep_kernel<<<(total + 255) / 256, 256, 0, stream>>>(
        h, hf, W1, W2, W3, Wn1, Wn2, b3,
        w1st, w1dt, w2t, wn1c, wn2t, b3n, ei, counts);
  }
  bsum_kernel<<<NB1, 1024, 0, stream>>>(counts, bsum);
  offs_kernel<<<NB1, 1024, 0, stream>>>(counts, bsum, cursor);
  h1p_kernel<<<2 * NB_H1 + NB_PERM + NB_ZERO, 256, 0, stream>>>(
      hf, b1, w1st, w1dt, H1s, H1d, ei, cursor, pairs, agg2);
  edge_kernel<<<NE / 128, 128, 0, stream>>>(H1s, H1d, pairs, w2t, b2, agg2);
  node_kernel<<<(NV + 255) / 256, 256, 0, stream>>>(hf, agg2, counts, wn1c, bn1, b3n,
                                                    wn2t, bn2, out);
}